// Round 2
// baseline (592.087 us; speedup 1.0000x reference)
//
#include <hip/hip_runtime.h>
#include <math.h>

#define QQ     1000
#define BBATCH 8
#define NTOT   21760

// ---------------------------------------------------------------------------
// Generic fp32 GEMM, K fixed = 256, row-major A (M x 256), B (256 x N),
// bias (N), C rows permuted: out_row = (r % rmod)*rmul + r/rmod.
//   value proj: rmod=8,    rmul=21760  (r = n*8+b  -> b*21760+n)
//   identity:   rmod=2^30, rmul=1
//   out proj:   rmod=1000, rmul=8      (r = b*1000+q -> q*8+b)
// 256 threads, 16x16 thread grid, micro-tile = (TM/16)x(TN/16) as 4-groups.
// ---------------------------------------------------------------------------
template<int TM, int TN>
__global__ __launch_bounds__(256) void gemm_bias_k256(
    const float* __restrict__ A, const float* __restrict__ Bw,
    const float* __restrict__ bias, float* __restrict__ C,
    const int M, const int N, const int rmod, const int rmul)
{
    constexpr int TK = 16;
    constexpr int GM = TM / 64;          // row 4-groups per thread
    constexpr int GN = TN / 64;          // col 4-groups per thread
    constexpr int MM = GM * 4;
    constexpr int MN = GN * 4;
    constexpr int LDA = TM + 4;          // As row length (padded, 16B aligned)
    constexpr int LDB = TN + 4;

    __shared__ float As[TK][LDA];        // transposed: As[k][m]
    __shared__ float Bs[TK][LDB];        // Bs[k][n]

    const int tid = threadIdx.x;
    const int tx = tid & 15;
    const int ty = tid >> 4;
    const int m0 = blockIdx.x * TM;
    const int n0 = blockIdx.y * TN;

    float acc[MM][MN];
#pragma unroll
    for (int i = 0; i < MM; ++i)
#pragma unroll
        for (int j = 0; j < MN; ++j) acc[i][j] = 0.f;

    constexpr int LA = TM / 64;          // float4 A loads per thread
    constexpr int LB = TN / 64;          // float4 B loads per thread
    constexpr int B4PR = TN / 4;         // float4s per B row

    for (int kc = 0; kc < 256; kc += TK) {
        __syncthreads();
        // A tile: TM x 16, float4 along K, store transposed into LDS
#pragma unroll
        for (int u = 0; u < LA; ++u) {
            const int idx = tid + u * 256;
            const int row = idx >> 2;
            const int c4  = (idx & 3) * 4;
            const float4 av = *reinterpret_cast<const float4*>(
                &A[(size_t)(m0 + row) * 256 + kc + c4]);
            As[c4 + 0][row] = av.x;
            As[c4 + 1][row] = av.y;
            As[c4 + 2][row] = av.z;
            As[c4 + 3][row] = av.w;
        }
        // B tile: 16 x TN, fully coalesced float4 rows
#pragma unroll
        for (int u = 0; u < LB; ++u) {
            const int idx = tid + u * 256;
            const int row = idx / B4PR;
            const int c4  = (idx % B4PR) * 4;
            const float4 bv = *reinterpret_cast<const float4*>(
                &Bw[(size_t)(kc + row) * N + n0 + c4]);
            *reinterpret_cast<float4*>(&Bs[row][c4]) = bv;
        }
        __syncthreads();
#pragma unroll
        for (int k = 0; k < TK; ++k) {
            float a[MM], b[MN];
#pragma unroll
            for (int g = 0; g < GM; ++g) {
                const float4 v = *reinterpret_cast<const float4*>(&As[k][ty * 4 + g * 64]);
                a[g*4+0] = v.x; a[g*4+1] = v.y; a[g*4+2] = v.z; a[g*4+3] = v.w;
            }
#pragma unroll
            for (int g = 0; g < GN; ++g) {
                const float4 v = *reinterpret_cast<const float4*>(&Bs[k][tx * 4 + g * 64]);
                b[g*4+0] = v.x; b[g*4+1] = v.y; b[g*4+2] = v.z; b[g*4+3] = v.w;
            }
#pragma unroll
            for (int i = 0; i < MM; ++i)
#pragma unroll
                for (int j = 0; j < MN; ++j)
                    acc[i][j] = fmaf(a[i], b[j], acc[i][j]);
        }
    }

    // epilogue: bias + permuted row store, float4 cols
#pragma unroll
    for (int gi = 0; gi < GM; ++gi)
#pragma unroll
        for (int ii = 0; ii < 4; ++ii) {
            const int gr = m0 + ty * 4 + gi * 64 + ii;
            const int orow = (gr % rmod) * rmul + gr / rmod;
#pragma unroll
            for (int gj = 0; gj < GN; ++gj) {
                const int col = n0 + tx * 4 + gj * 64;
                float4 o;
                o.x = acc[gi*4+ii][gj*4+0] + bias[col + 0];
                o.y = acc[gi*4+ii][gj*4+1] + bias[col + 1];
                o.z = acc[gi*4+ii][gj*4+2] + bias[col + 2];
                o.w = acc[gi*4+ii][gj*4+3] + bias[col + 3];
                *reinterpret_cast<float4*>(&C[(size_t)orow * N + col]) = o;
            }
        }
}

// ---------------------------------------------------------------------------
// Sampling: one wave per (b, q, h).  64000 waves = 16000 blocks x 4 waves.
// Lanes (replicated x4 via lane&15) compute softmax over the head's 16
// (level,point) logits + sampling coords; then lane = half*32+c accumulates
// 8 samples x channel c; half-wave reduce; lanes 0-31 store 32 channels.
// Spatial shapes are fixed by the problem: W=H=128>>l, start=(65536-(65536>>2l))/3.
// ---------------------------------------------------------------------------
__global__ __launch_bounds__(256) void msda_sample(
    const float* __restrict__ vproj, const float* __restrict__ off_raw,
    const float* __restrict__ attn_raw, const float* __restrict__ refp,
    float* __restrict__ tmp)
{
    const int lane = threadIdx.x & 63;
    const int widx = blockIdx.x * 4 + (threadIdx.x >> 6);
    const int h  = widx & 7;
    const int bq = widx >> 3;                 // b*QQ + qi
    const int b  = bq / QQ;
    const int qi = bq - b * QQ;
    const int row_q = qi * BBATCH + b;        // row in query-side projections

    // --- per-sample metadata (sample s = lane & 15) ---
    const int s0 = lane & 15;
    const int l0 = s0 >> 2;
    float a = attn_raw[row_q * 128 + h * 16 + s0];
    float m = a;
#pragma unroll
    for (int msk = 8; msk >= 1; msk >>= 1) m = fmaxf(m, __shfl_xor(m, msk));
    const float e = __expf(a - m);
    float ssum = e;
#pragma unroll
    for (int msk = 8; msk >= 1; msk >>= 1) ssum += __shfl_xor(ssum, msk);
    const float wv = e / ssum;

    const float offx = off_raw[row_q * 256 + (h * 16 + s0) * 2 + 0];
    const float offy = off_raw[row_q * 256 + (h * 16 + s0) * 2 + 1];
    const float rx = refp[row_q * 2 + 0];
    const float ry = refp[row_q * 2 + 1];
    const float Wf = (float)(128 >> l0);      // H == W at every level
    float lx = rx + offx / (Wf + 1e-6f);
    float ly = ry + offy / (Wf + 1e-6f);
    lx = fminf(fmaxf(lx, 0.f), 1.f);
    ly = fminf(fmaxf(ly, 0.f), 1.f);
    const float xv = lx * Wf - 0.5f;          // grid_sample align_corners=False
    const float yv = ly * Wf - 0.5f;

    // --- bilinear accumulation: half-wave handles 8 samples, 32 channels ---
    const int c = lane & 31;
    const int sbase = (lane >> 5) * 8;
    const float* __restrict__ vb = vproj + (size_t)b * NTOT * 256 + h * 32 + c;

    float acc = 0.f;
#pragma unroll
    for (int i = 0; i < 8; ++i) {
        const int s = sbase + i;
        const float xs = __shfl(xv, s);
        const float ys = __shfl(yv, s);
        const float ws = __shfl(wv, s);
        const int l = s >> 2;
        const int Wl = 128 >> l;
        const int start = (65536 - (65536 >> (2 * l))) / 3;
        const float x0f = floorf(xs), y0f = floorf(ys);
        const float fx = xs - x0f, fy = ys - y0f;
        const int x0 = (int)x0f, y0 = (int)y0f;
        const int x1 = x0 + 1,   y1 = y0 + 1;
        const float vx0 = (x0 >= 0 && x0 < Wl) ? 1.f : 0.f;
        const float vx1 = (x1 >= 0 && x1 < Wl) ? 1.f : 0.f;
        const float vy0 = (y0 >= 0 && y0 < Wl) ? 1.f : 0.f;
        const float vy1 = (y1 >= 0 && y1 < Wl) ? 1.f : 0.f;
        const int xc0 = min(max(x0, 0), Wl - 1);
        const int xc1 = min(max(x1, 0), Wl - 1);
        const int yc0 = min(max(y0, 0), Wl - 1);
        const int yc1 = min(max(y1, 0), Wl - 1);
        const float* base = vb + (size_t)start * 256;
        const float v00 = base[(size_t)(yc0 * Wl + xc0) * 256];
        const float v10 = base[(size_t)(yc0 * Wl + xc1) * 256];
        const float v01 = base[(size_t)(yc1 * Wl + xc0) * 256];
        const float v11 = base[(size_t)(yc1 * Wl + xc1) * 256];
        const float w00 = (1.f - fx) * (1.f - fy) * vx0 * vy0;
        const float w10 = fx * (1.f - fy) * vx1 * vy0;
        const float w01 = (1.f - fx) * fy * vx0 * vy1;
        const float w11 = fx * fy * vx1 * vy1;
        acc += ws * (w00 * v00 + w10 * v10 + w01 * v01 + w11 * v11);
    }
    acc += __shfl_xor(acc, 32);               // combine the two sample-halves
    if (lane < 32) tmp[(size_t)bq * 256 + h * 32 + c] = acc;
}

// ---------------------------------------------------------------------------
extern "C" void kernel_launch(void* const* d_in, const int* in_sizes, int n_in,
                              void* d_out, int out_size, void* d_ws, size_t ws_size,
                              hipStream_t stream) {
    (void)in_sizes; (void)n_in; (void)out_size; (void)ws_size;

    const float* query  = (const float*)d_in[0];
    const float* refp   = (const float*)d_in[1];
    const float* value  = (const float*)d_in[2];
    // d_in[3] spatial_shapes, d_in[4] level_start_idx: fixed by problem, hardcoded
    const float* W_v    = (const float*)d_in[5];
    const float* b_v    = (const float*)d_in[6];
    const float* W_off  = (const float*)d_in[7];
    const float* b_off  = (const float*)d_in[8];
    const float* W_attn = (const float*)d_in[9];
    const float* b_attn = (const float*)d_in[10];
    const float* W_out  = (const float*)d_in[11];
    const float* b_out  = (const float*)d_in[12];
    float* out = (float*)d_out;

    // workspace layout (floats): vproj 44,564,480 | off 2,048,000 |
    // attn 1,024,000 | tmp 2,048,000  -> 198.7 MB total
    float* vproj    = (float*)d_ws;
    float* off_raw  = vproj + (size_t)44564480;
    float* attn_raw = off_raw + 2048000;
    float* tmp      = attn_raw + 1024000;

    const dim3 blk(256);
    // value projection: (174080 x 256) @ (256 x 256), row remap n*8+b -> b*21760+n
    gemm_bias_k256<128,128><<<dim3(1360, 2), blk, 0, stream>>>(
        value, W_v, b_v, vproj, 174080, 256, 8, 21760);
    // offsets: (8000 x 256) @ (256 x 256), identity rows
    gemm_bias_k256<64,64><<<dim3(125, 4), blk, 0, stream>>>(
        query, W_off, b_off, off_raw, 8000, 256, 1 << 30, 1);
    // attention logits: (8000 x 256) @ (256 x 128), identity rows
    gemm_bias_k256<64,64><<<dim3(125, 2), blk, 0, stream>>>(
        query, W_attn, b_attn, attn_raw, 8000, 128, 1 << 30, 1);
    // sampling: 64000 waves
    msda_sample<<<dim3(16000), blk, 0, stream>>>(vproj, off_raw, attn_raw, refp, tmp);
    // output projection: (8000 x 256) @ (256 x 256), row remap b*1000+q -> q*8+b
    gemm_bias_k256<64,64><<<dim3(125, 4), blk, 0, stream>>>(
        tmp, W_out, b_out, out, 8000, 256, 1000, 8);
}

// Round 3
// 448.329 us; speedup vs baseline: 1.3207x; 1.3207x over previous
//
#include <hip/hip_runtime.h>
#include <math.h>

#define QQ     1000
#define BBATCH 8
#define NTOT   21760

typedef __bf16 bf16x8 __attribute__((ext_vector_type(8)));
typedef float  f32x4  __attribute__((ext_vector_type(4)));

// fp32 -> bf16 (RNE) hi part, remainder out
__device__ __forceinline__ unsigned short bf_hi(float f, float* rem) {
    unsigned u = __builtin_bit_cast(unsigned, f);
    unsigned r = (u + 0x7FFFu + ((u >> 16) & 1u)) >> 16;
    float hf = __builtin_bit_cast(float, r << 16);
    *rem = f - hf;
    return (unsigned short)r;
}
__device__ __forceinline__ unsigned short bf_rn(float f) {
    unsigned u = __builtin_bit_cast(unsigned, f);
    return (unsigned short)((u + 0x7FFFu + ((u >> 16) & 1u)) >> 16);
}

// ---------------------------------------------------------------------------
// Pre-pass: W_v (256k x 256n fp32) -> Bt_hi/Bt_lo bf16, layout [n][k],
// XOR-swizzled per 64-k chunk: 16B slot s stored at s^(n&7).
// Grid: 32 blocks x 256 threads; thread = (n = blk*8 + tid>>5, oct = tid&31).
// ---------------------------------------------------------------------------
__global__ __launch_bounds__(256) void conv_wv(
    const float* __restrict__ Wv,
    unsigned short* __restrict__ Bh, unsigned short* __restrict__ Bl)
{
    const int tid = threadIdx.x;
    const int n   = blockIdx.x * 8 + (tid >> 5);
    const int oct = tid & 31;
    const int k0  = oct * 8;
    float r0, r1, r2, r3, r4, r5, r6, r7;
    const unsigned h0 = bf_hi(Wv[(k0+0)*256 + n], &r0);
    const unsigned h1 = bf_hi(Wv[(k0+1)*256 + n], &r1);
    const unsigned h2 = bf_hi(Wv[(k0+2)*256 + n], &r2);
    const unsigned h3 = bf_hi(Wv[(k0+3)*256 + n], &r3);
    const unsigned h4 = bf_hi(Wv[(k0+4)*256 + n], &r4);
    const unsigned h5 = bf_hi(Wv[(k0+5)*256 + n], &r5);
    const unsigned h6 = bf_hi(Wv[(k0+6)*256 + n], &r6);
    const unsigned h7 = bf_hi(Wv[(k0+7)*256 + n], &r7);
    uint4 hv, lv;
    hv.x = h0 | (h1 << 16); hv.y = h2 | (h3 << 16);
    hv.z = h4 | (h5 << 16); hv.w = h6 | (h7 << 16);
    lv.x = (unsigned)bf_rn(r0) | ((unsigned)bf_rn(r1) << 16);
    lv.y = (unsigned)bf_rn(r2) | ((unsigned)bf_rn(r3) << 16);
    lv.z = (unsigned)bf_rn(r4) | ((unsigned)bf_rn(r5) << 16);
    lv.w = (unsigned)bf_rn(r6) | ((unsigned)bf_rn(r7) << 16);
    const int c  = oct >> 3;
    const int sp = (oct & 7) ^ (n & 7);
    const size_t byte = (size_t)n * 512 + (size_t)c * 128 + (size_t)sp * 16;
    *reinterpret_cast<uint4*>((char*)Bh + byte) = hv;
    *reinterpret_cast<uint4*>((char*)Bl + byte) = lv;
}

// ---------------------------------------------------------------------------
// Value projection via bf16x3 MFMA.
// A = value (M x 256 fp32), Bt = pre-converted W_v^T bf16 hi/lo (swizzled).
// Tile BM=64 x BN=256, BK=64; 4 waves along N (64 cols each, 4x4 frags of
// 16x16x32). C rows remapped r=n*8+b -> b*21760+n. LDS 80 KB, 2 blocks/CU.
// ---------------------------------------------------------------------------
__global__ __launch_bounds__(256, 2) void gemm_value_mfma(
    const float* __restrict__ A,
    const unsigned short* __restrict__ Bth, const unsigned short* __restrict__ Btl,
    const float* __restrict__ bias, float* __restrict__ C)
{
    __shared__ unsigned short Ah_lds[64 * 64];     // 8 KB  [row][k] swizzled
    __shared__ unsigned short Al_lds[64 * 64];     // 8 KB
    __shared__ unsigned short Bh_lds[256 * 64];    // 32 KB [n][k] swizzled
    __shared__ unsigned short Bl_lds[256 * 64];    // 32 KB

    const int tid  = threadIdx.x;
    const int lane = tid & 63;
    const int w    = tid >> 6;
    const int m0   = blockIdx.x * 64;

    f32x4 acc[4][4];
#pragma unroll
    for (int i = 0; i < 4; ++i)
#pragma unroll
        for (int j = 0; j < 4; ++j) acc[i][j] = (f32x4){0.f, 0.f, 0.f, 0.f};

    for (int kc = 0; kc < 256; kc += 64) {
        __syncthreads();                            // LDS reuse guard
        // --- A stage: fp32 load -> split bf16 -> swizzled ds_write ---
#pragma unroll
        for (int u = 0; u < 4; ++u) {
            const int idx = tid + u * 256;          // 0..1023
            const int row = idx >> 4;               // 0..63
            const int c4  = (idx & 15) * 4;         // 0..60
            const float4 av = *reinterpret_cast<const float4*>(
                &A[(size_t)(m0 + row) * 256 + kc + c4]);
            float r0, r1, r2, r3;
            const unsigned e0 = bf_hi(av.x, &r0);
            const unsigned e1 = bf_hi(av.y, &r1);
            const unsigned e2 = bf_hi(av.z, &r2);
            const unsigned e3 = bf_hi(av.w, &r3);
            uint2 hp, lp;
            hp.x = e0 | (e1 << 16);
            hp.y = e2 | (e3 << 16);
            lp.x = (unsigned)bf_rn(r0) | ((unsigned)bf_rn(r1) << 16);
            lp.y = (unsigned)bf_rn(r2) | ((unsigned)bf_rn(r3) << 16);
            const unsigned byte = (unsigned)(row * 128 + c4 * 2) ^ ((unsigned)(row & 7) << 4);
            *reinterpret_cast<uint2*>((char*)Ah_lds + byte) = hp;
            *reinterpret_cast<uint2*>((char*)Al_lds + byte) = lp;
        }
        // --- B stage: linear global_load_lds (source pre-swizzled) ---
        {
            const int r8 = lane >> 3, sl = lane & 7;
#pragma unroll
            for (int i = 0; i < 16; ++i) {
                const int chunk = w * 16 + i;       // 0..63 (32 hi + 32 lo)
                const int plane = chunk >> 5;
                const int crow  = (chunk & 31) * 8;
                const unsigned short* gb = plane ? Btl : Bth;
                const size_t gbyte = (size_t)(crow + r8) * 512 + (size_t)kc * 2 + (size_t)sl * 16;
                unsigned short* lbase = (plane ? Bl_lds : Bh_lds) + crow * 64;
                __builtin_amdgcn_global_load_lds(
                    (const __attribute__((address_space(1))) void*)((const char*)gb + gbyte),
                    (__attribute__((address_space(3))) void*)lbase,
                    16, 0, 0);
            }
        }
        __syncthreads();                            // drains vmcnt+lgkmcnt
        // --- compute: 2 k-chunks x 16 frags x 3 passes ---
#pragma unroll
        for (int kk = 0; kk < 2; ++kk) {
            bf16x8 ah[4], al[4], bh[4], bl[4];
            const int slot = kk * 4 + (lane >> 4);
#pragma unroll
            for (int fr = 0; fr < 4; ++fr) {
                const int row = fr * 16 + (lane & 15);
                const unsigned byte = (unsigned)(row * 128) + ((unsigned)(slot ^ (row & 7)) << 4);
                ah[fr] = *reinterpret_cast<const bf16x8*>((const char*)Ah_lds + byte);
                al[fr] = *reinterpret_cast<const bf16x8*>((const char*)Al_lds + byte);
            }
#pragma unroll
            for (int fc = 0; fc < 4; ++fc) {
                const int n = w * 64 + fc * 16 + (lane & 15);
                const unsigned byte = (unsigned)(n * 128) + ((unsigned)(slot ^ (n & 7)) << 4);
                bh[fc] = *reinterpret_cast<const bf16x8*>((const char*)Bh_lds + byte);
                bl[fc] = *reinterpret_cast<const bf16x8*>((const char*)Bl_lds + byte);
            }
#pragma unroll
            for (int fr = 0; fr < 4; ++fr)
#pragma unroll
                for (int fc = 0; fc < 4; ++fc) {
                    acc[fr][fc] = __builtin_amdgcn_mfma_f32_16x16x32_bf16(ah[fr], bh[fc], acc[fr][fc], 0, 0, 0);
                    acc[fr][fc] = __builtin_amdgcn_mfma_f32_16x16x32_bf16(al[fr], bh[fc], acc[fr][fc], 0, 0, 0);
                    acc[fr][fc] = __builtin_amdgcn_mfma_f32_16x16x32_bf16(ah[fr], bl[fc], acc[fr][fc], 0, 0, 0);
                }
        }
    }
    // epilogue: bias + permuted-row scalar stores (lanes 0-15 = contiguous cols)
#pragma unroll
    for (int fc = 0; fc < 4; ++fc) {
        const int col = w * 64 + fc * 16 + (lane & 15);
        const float bv = bias[col];
#pragma unroll
        for (int fr = 0; fr < 4; ++fr)
#pragma unroll
            for (int ri = 0; ri < 4; ++ri) {
                const int gr = m0 + fr * 16 + (lane >> 4) * 4 + ri;   // r = n*8+b
                const int orow = (gr & 7) * NTOT + (gr >> 3);         // b*21760+n
                C[(size_t)orow * 256 + col] = acc[fr][fc][ri] + bv;
            }
    }
}

// ---------------------------------------------------------------------------
// fp32 GEMM (unchanged) for the small query-side projections.
// ---------------------------------------------------------------------------
template<int TM, int TN>
__global__ __launch_bounds__(256) void gemm_bias_k256(
    const float* __restrict__ A, const float* __restrict__ Bw,
    const float* __restrict__ bias, float* __restrict__ C,
    const int M, const int N, const int rmod, const int rmul)
{
    constexpr int TK = 16;
    constexpr int GM = TM / 64;
    constexpr int GN = TN / 64;
    constexpr int MM = GM * 4;
    constexpr int MN = GN * 4;
    constexpr int LDA = TM + 4;
    constexpr int LDB = TN + 4;

    __shared__ float As[TK][LDA];
    __shared__ float Bs[TK][LDB];

    const int tid = threadIdx.x;
    const int tx = tid & 15;
    const int ty = tid >> 4;
    const int m0 = blockIdx.x * TM;
    const int n0 = blockIdx.y * TN;

    float acc[MM][MN];
#pragma unroll
    for (int i = 0; i < MM; ++i)
#pragma unroll
        for (int j = 0; j < MN; ++j) acc[i][j] = 0.f;

    constexpr int LA = TM / 64;
    constexpr int LB = TN / 64;
    constexpr int B4PR = TN / 4;

    for (int kc = 0; kc < 256; kc += TK) {
        __syncthreads();
#pragma unroll
        for (int u = 0; u < LA; ++u) {
            const int idx = tid + u * 256;
            const int row = idx >> 2;
            const int c4  = (idx & 3) * 4;
            const float4 av = *reinterpret_cast<const float4*>(
                &A[(size_t)(m0 + row) * 256 + kc + c4]);
            As[c4 + 0][row] = av.x;
            As[c4 + 1][row] = av.y;
            As[c4 + 2][row] = av.z;
            As[c4 + 3][row] = av.w;
        }
#pragma unroll
        for (int u = 0; u < LB; ++u) {
            const int idx = tid + u * 256;
            const int row = idx / B4PR;
            const int c4  = (idx % B4PR) * 4;
            const float4 bv = *reinterpret_cast<const float4*>(
                &Bw[(size_t)(kc + row) * N + n0 + c4]);
            *reinterpret_cast<float4*>(&Bs[row][c4]) = bv;
        }
        __syncthreads();
#pragma unroll
        for (int k = 0; k < TK; ++k) {
            float a[MM], b[MN];
#pragma unroll
            for (int g = 0; g < GM; ++g) {
                const float4 v = *reinterpret_cast<const float4*>(&As[k][ty * 4 + g * 64]);
                a[g*4+0] = v.x; a[g*4+1] = v.y; a[g*4+2] = v.z; a[g*4+3] = v.w;
            }
#pragma unroll
            for (int g = 0; g < GN; ++g) {
                const float4 v = *reinterpret_cast<const float4*>(&Bs[k][tx * 4 + g * 64]);
                b[g*4+0] = v.x; b[g*4+1] = v.y; b[g*4+2] = v.z; b[g*4+3] = v.w;
            }
#pragma unroll
            for (int i = 0; i < MM; ++i)
#pragma unroll
                for (int j = 0; j < MN; ++j)
                    acc[i][j] = fmaf(a[i], b[j], acc[i][j]);
        }
    }

#pragma unroll
    for (int gi = 0; gi < GM; ++gi)
#pragma unroll
        for (int ii = 0; ii < 4; ++ii) {
            const int gr = m0 + ty * 4 + gi * 64 + ii;
            const int orow = (gr % rmod) * rmul + gr / rmod;
#pragma unroll
            for (int gj = 0; gj < GN; ++gj) {
                const int col = n0 + tx * 4 + gj * 64;
                float4 o;
                o.x = acc[gi*4+ii][gj*4+0] + bias[col + 0];
                o.y = acc[gi*4+ii][gj*4+1] + bias[col + 1];
                o.z = acc[gi*4+ii][gj*4+2] + bias[col + 2];
                o.w = acc[gi*4+ii][gj*4+3] + bias[col + 3];
                *reinterpret_cast<float4*>(&C[(size_t)orow * N + col]) = o;
            }
        }
}

// ---------------------------------------------------------------------------
// Sampling (unchanged): one wave per (b, q, h).
// ---------------------------------------------------------------------------
__global__ __launch_bounds__(256) void msda_sample(
    const float* __restrict__ vproj, const float* __restrict__ off_raw,
    const float* __restrict__ attn_raw, const float* __restrict__ refp,
    float* __restrict__ tmp)
{
    const int lane = threadIdx.x & 63;
    const int widx = blockIdx.x * 4 + (threadIdx.x >> 6);
    const int h  = widx & 7;
    const int bq = widx >> 3;
    const int b  = bq / QQ;
    const int qi = bq - b * QQ;
    const int row_q = qi * BBATCH + b;

    const int s0 = lane & 15;
    const int l0 = s0 >> 2;
    float a = attn_raw[row_q * 128 + h * 16 + s0];
    float m = a;
#pragma unroll
    for (int msk = 8; msk >= 1; msk >>= 1) m = fmaxf(m, __shfl_xor(m, msk));
    const float e = __expf(a - m);
    float ssum = e;
#pragma unroll
    for (int msk = 8; msk >= 1; msk >>= 1) ssum += __shfl_xor(ssum, msk);
    const float wv = e / ssum;

    const float offx = off_raw[row_q * 256 + (h * 16 + s0) * 2 + 0];
    const float offy = off_raw[row_q * 256 + (h * 16 + s0) * 2 + 1];
    const float rx = refp[row_q * 2 + 0];
    const float ry = refp[row_q * 2 + 1];
    const float Wf = (float)(128 >> l0);
    float lx = rx + offx / (Wf + 1e-6f);
    float ly = ry + offy / (Wf + 1e-6f);
    lx = fminf(fmaxf(lx, 0.f), 1.f);
    ly = fminf(fmaxf(ly, 0.f), 1.f);
    const float xv = lx * Wf - 0.5f;
    const float yv = ly * Wf - 0.5f;

    const int c = lane & 31;
    const int sbase = (lane >> 5) * 8;
    const float* __restrict__ vb = vproj + (size_t)b * NTOT * 256 + h * 32 + c;

    float acc = 0.f;
#pragma unroll
    for (int i = 0; i < 8; ++i) {
        const int s = sbase + i;
        const float xs = __shfl(xv, s);
        const float ys = __shfl(yv, s);
        const float ws = __shfl(wv, s);
        const int l = s >> 2;
        const int Wl = 128 >> l;
        const int start = (65536 - (65536 >> (2 * l))) / 3;
        const float x0f = floorf(xs), y0f = floorf(ys);
        const float fx = xs - x0f, fy = ys - y0f;
        const int x0 = (int)x0f, y0 = (int)y0f;
        const int x1 = x0 + 1,   y1 = y0 + 1;
        const float vx0 = (x0 >= 0 && x0 < Wl) ? 1.f : 0.f;
        const float vx1 = (x1 >= 0 && x1 < Wl) ? 1.f : 0.f;
        const float vy0 = (y0 >= 0 && y0 < Wl) ? 1.f : 0.f;
        const float vy1 = (y1 >= 0 && y1 < Wl) ? 1.f : 0.f;
        const int xc0 = min(max(x0, 0), Wl - 1);
        const int xc1 = min(max(x1, 0), Wl - 1);
        const int yc0 = min(max(y0, 0), Wl - 1);
        const int yc1 = min(max(y1, 0), Wl - 1);
        const float* base = vb + (size_t)start * 256;
        const float v00 = base[(size_t)(yc0 * Wl + xc0) * 256];
        const float v10 = base[(size_t)(yc0 * Wl + xc1) * 256];
        const float v01 = base[(size_t)(yc1 * Wl + xc0) * 256];
        const float v11 = base[(size_t)(yc1 * Wl + xc1) * 256];
        const float w00 = (1.f - fx) * (1.f - fy) * vx0 * vy0;
        const float w10 = fx * (1.f - fy) * vx1 * vy0;
        const float w01 = (1.f - fx) * fy * vx0 * vy1;
        const float w11 = fx * fy * vx1 * vy1;
        acc += ws * (w00 * v00 + w10 * v10 + w01 * v01 + w11 * v11);
    }
    acc += __shfl_xor(acc, 32);
    if (lane < 32) tmp[(size_t)bq * 256 + h * 32 + c] = acc;
}

// ---------------------------------------------------------------------------
extern "C" void kernel_launch(void* const* d_in, const int* in_sizes, int n_in,
                              void* d_out, int out_size, void* d_ws, size_t ws_size,
                              hipStream_t stream) {
    (void)in_sizes; (void)n_in; (void)out_size; (void)ws_size;

    const float* query  = (const float*)d_in[0];
    const float* refp   = (const float*)d_in[1];
    const float* value  = (const float*)d_in[2];
    const float* W_v    = (const float*)d_in[5];
    const float* b_v    = (const float*)d_in[6];
    const float* W_off  = (const float*)d_in[7];
    const float* b_off  = (const float*)d_in[8];
    const float* W_attn = (const float*)d_in[9];
    const float* b_attn = (const float*)d_in[10];
    const float* W_out  = (const float*)d_in[11];
    const float* b_out  = (const float*)d_in[12];
    float* out = (float*)d_out;

    // workspace (floats): vproj 44,564,480 | off 2,048,000 | attn 1,024,000 |
    // tmp 2,048,000.  Bt_hi/Bt_lo (128 KB each) live in tmp's first 256 KB:
    // read only by the value GEMM, overwritten later by the sampler — safe.
    float* vproj    = (float*)d_ws;
    float* off_raw  = vproj + (size_t)44564480;
    float* attn_raw = off_raw + 2048000;
    float* tmp      = attn_raw + 1024000;
    unsigned short* Bt_h = (unsigned short*)tmp;
    unsigned short* Bt_l = Bt_h + 65536;

    const dim3 blk(256);
    // W_v -> transposed split-bf16, swizzled
    conv_wv<<<dim3(32), blk, 0, stream>>>(W_v, Bt_h, Bt_l);
    // value projection via bf16x3 MFMA: (174080 x 256) @ (256 x 256)
    gemm_value_mfma<<<dim3(2720), blk, 0, stream>>>(value, Bt_h, Bt_l, b_v, vproj);
    // offsets: (8000 x 256) @ (256 x 256)
    gemm_bias_k256<64,64><<<dim3(125, 4), blk, 0, stream>>>(
        query, W_off, b_off, off_raw, 8000, 256, 1 << 30, 1);
    // attention logits: (8000 x 256) @ (256 x 128)
    gemm_bias_k256<64,64><<<dim3(125, 2), blk, 0, stream>>>(
        query, W_attn, b_attn, attn_raw, 8000, 128, 1 << 30, 1);
    // sampling: 64000 waves
    msda_sample<<<dim3(16000), blk, 0, stream>>>(vproj, off_raw, attn_raw, refp, tmp);
    // output projection: (8000 x 256) @ (256 x 256), rows b*1000+q -> q*8+b
    gemm_bias_k256<64,64><<<dim3(125, 4), blk, 0, stream>>>(
        tmp, W_out, b_out, out, 8000, 256, 1000, 8);
}

// Round 9
// 433.177 us; speedup vs baseline: 1.3668x; 1.0350x over previous
//
#include <hip/hip_runtime.h>
#include <math.h>

#define QQ     1000
#define BBATCH 8
#define NTOT   21760

typedef __bf16 bf16x8 __attribute__((ext_vector_type(8)));
typedef float  f32x4  __attribute__((ext_vector_type(4)));

// fp32 -> bf16 (RNE) hi part, remainder out
__device__ __forceinline__ unsigned short bf_hi(float f, float* rem) {
    unsigned u = __builtin_bit_cast(unsigned, f);
    unsigned r = (u + 0x7FFFu + ((u >> 16) & 1u)) >> 16;
    float hf = __builtin_bit_cast(float, r << 16);
    *rem = f - hf;
    return (unsigned short)r;
}
__device__ __forceinline__ unsigned short bf_rn(float f) {
    unsigned u = __builtin_bit_cast(unsigned, f);
    return (unsigned short)((u + 0x7FFFu + ((u >> 16) & 1u)) >> 16);
}

// ---------------------------------------------------------------------------
// Pre-pass A: W_v (256k x 256n fp32) -> Bt_hi/Bt_lo bf16, layout [n][k],
// XOR-swizzled per 64-k chunk: 16B slot s stored at s^(n&7).
// ---------------------------------------------------------------------------
__global__ __launch_bounds__(256) void conv_wv(
    const float* __restrict__ Wv,
    unsigned short* __restrict__ Bh, unsigned short* __restrict__ Bl)
{
    const int tid = threadIdx.x;
    const int n   = blockIdx.x * 8 + (tid >> 5);
    const int oct = tid & 31;
    const int k0  = oct * 8;
    float r0, r1, r2, r3, r4, r5, r6, r7;
    const unsigned h0 = bf_hi(Wv[(k0+0)*256 + n], &r0);
    const unsigned h1 = bf_hi(Wv[(k0+1)*256 + n], &r1);
    const unsigned h2 = bf_hi(Wv[(k0+2)*256 + n], &r2);
    const unsigned h3 = bf_hi(Wv[(k0+3)*256 + n], &r3);
    const unsigned h4 = bf_hi(Wv[(k0+4)*256 + n], &r4);
    const unsigned h5 = bf_hi(Wv[(k0+5)*256 + n], &r5);
    const unsigned h6 = bf_hi(Wv[(k0+6)*256 + n], &r6);
    const unsigned h7 = bf_hi(Wv[(k0+7)*256 + n], &r7);
    uint4 hv, lv;
    hv.x = h0 | (h1 << 16); hv.y = h2 | (h3 << 16);
    hv.z = h4 | (h5 << 16); hv.w = h6 | (h7 << 16);
    lv.x = (unsigned)bf_rn(r0) | ((unsigned)bf_rn(r1) << 16);
    lv.y = (unsigned)bf_rn(r2) | ((unsigned)bf_rn(r3) << 16);
    lv.z = (unsigned)bf_rn(r4) | ((unsigned)bf_rn(r5) << 16);
    lv.w = (unsigned)bf_rn(r6) | ((unsigned)bf_rn(r7) << 16);
    const int c  = oct >> 3;
    const int sp = (oct & 7) ^ (n & 7);
    const size_t byte = (size_t)n * 512 + (size_t)c * 128 + (size_t)sp * 16;
    *reinterpret_cast<uint4*>((char*)Bh + byte) = hv;
    *reinterpret_cast<uint4*>((char*)Bl + byte) = lv;
}

// ---------------------------------------------------------------------------
// Pre-pass B: [W_off(256n) | W_attn(128n) | W_out(256n)] -> 640-row cat buffer,
// same transposed/swizzled hi-lo layout. Grid 80 x 256.
// ---------------------------------------------------------------------------
__global__ __launch_bounds__(256) void conv_wcat(
    const float* __restrict__ W_off, const float* __restrict__ W_attn,
    const float* __restrict__ W_out,
    unsigned short* __restrict__ Bh, unsigned short* __restrict__ Bl)
{
    const int tid = threadIdx.x;
    const int n   = blockIdx.x * 8 + (tid >> 5);
    const int oct = tid & 31;
    const int k0  = oct * 8;
    const float* src; int col, ld;
    if (n < 256)      { src = W_off;  col = n;       ld = 256; }
    else if (n < 384) { src = W_attn; col = n - 256; ld = 128; }
    else              { src = W_out;  col = n - 384; ld = 256; }
    unsigned hw[8], lw[8];
#pragma unroll
    for (int j = 0; j < 8; ++j) {
        float r;
        hw[j] = bf_hi(src[(size_t)(k0 + j) * ld + col], &r);
        lw[j] = bf_rn(r);
    }
    uint4 hv, lv;
    hv.x = hw[0] | (hw[1] << 16); hv.y = hw[2] | (hw[3] << 16);
    hv.z = hw[4] | (hw[5] << 16); hv.w = hw[6] | (hw[7] << 16);
    lv.x = lw[0] | (lw[1] << 16); lv.y = lw[2] | (lw[3] << 16);
    lv.z = lw[4] | (lw[5] << 16); lv.w = lw[6] | (lw[7] << 16);
    const int c  = oct >> 3;
    const int sp = (oct & 7) ^ (n & 7);
    const size_t byte = (size_t)n * 512 + (size_t)c * 128 + (size_t)sp * 16;
    *reinterpret_cast<uint4*>((char*)Bh + byte) = hv;
    *reinterpret_cast<uint4*>((char*)Bl + byte) = lv;
}

// ---------------------------------------------------------------------------
// Value projection via bf16x3 MFMA (unchanged from round 3; verified).
// ---------------------------------------------------------------------------
__global__ __launch_bounds__(256, 2) void gemm_value_mfma(
    const float* __restrict__ A,
    const unsigned short* __restrict__ Bth, const unsigned short* __restrict__ Btl,
    const float* __restrict__ bias, float* __restrict__ C)
{
    __shared__ unsigned short Ah_lds[64 * 64];
    __shared__ unsigned short Al_lds[64 * 64];
    __shared__ unsigned short Bh_lds[256 * 64];
    __shared__ unsigned short Bl_lds[256 * 64];

    const int tid  = threadIdx.x;
    const int lane = tid & 63;
    const int w    = tid >> 6;
    const int m0   = blockIdx.x * 64;

    f32x4 acc[4][4];
#pragma unroll
    for (int i = 0; i < 4; ++i)
#pragma unroll
        for (int j = 0; j < 4; ++j) acc[i][j] = (f32x4){0.f, 0.f, 0.f, 0.f};

    for (int kc = 0; kc < 256; kc += 64) {
        __syncthreads();
#pragma unroll
        for (int u = 0; u < 4; ++u) {
            const int idx = tid + u * 256;
            const int row = idx >> 4;
            const int c4  = (idx & 15) * 4;
            const float4 av = *reinterpret_cast<const float4*>(
                &A[(size_t)(m0 + row) * 256 + kc + c4]);
            float r0, r1, r2, r3;
            const unsigned e0 = bf_hi(av.x, &r0);
            const unsigned e1 = bf_hi(av.y, &r1);
            const unsigned e2 = bf_hi(av.z, &r2);
            const unsigned e3 = bf_hi(av.w, &r3);
            uint2 hp, lp;
            hp.x = e0 | (e1 << 16);
            hp.y = e2 | (e3 << 16);
            lp.x = (unsigned)bf_rn(r0) | ((unsigned)bf_rn(r1) << 16);
            lp.y = (unsigned)bf_rn(r2) | ((unsigned)bf_rn(r3) << 16);
            const unsigned byte = (unsigned)(row * 128 + c4 * 2) ^ ((unsigned)(row & 7) << 4);
            *reinterpret_cast<uint2*>((char*)Ah_lds + byte) = hp;
            *reinterpret_cast<uint2*>((char*)Al_lds + byte) = lp;
        }
        {
            const int r8 = lane >> 3, sl = lane & 7;
#pragma unroll
            for (int i = 0; i < 16; ++i) {
                const int chunk = w * 16 + i;
                const int plane = chunk >> 5;
                const int crow  = (chunk & 31) * 8;
                const unsigned short* gb = plane ? Btl : Bth;
                const size_t gbyte = (size_t)(crow + r8) * 512 + (size_t)kc * 2 + (size_t)sl * 16;
                unsigned short* lbase = (plane ? Bl_lds : Bh_lds) + crow * 64;
                __builtin_amdgcn_global_load_lds(
                    (const __attribute__((address_space(1))) void*)((const char*)gb + gbyte),
                    (__attribute__((address_space(3))) void*)lbase,
                    16, 0, 0);
            }
        }
        __syncthreads();
#pragma unroll
        for (int kk = 0; kk < 2; ++kk) {
            bf16x8 ah[4], al[4], bh[4], bl[4];
            const int slot = kk * 4 + (lane >> 4);
#pragma unroll
            for (int fr = 0; fr < 4; ++fr) {
                const int row = fr * 16 + (lane & 15);
                const unsigned byte = (unsigned)(row * 128) + ((unsigned)(slot ^ (row & 7)) << 4);
                ah[fr] = *reinterpret_cast<const bf16x8*>((const char*)Ah_lds + byte);
                al[fr] = *reinterpret_cast<const bf16x8*>((const char*)Al_lds + byte);
            }
#pragma unroll
            for (int fc = 0; fc < 4; ++fc) {
                const int n = w * 64 + fc * 16 + (lane & 15);
                const unsigned byte = (unsigned)(n * 128) + ((unsigned)(slot ^ (n & 7)) << 4);
                bh[fc] = *reinterpret_cast<const bf16x8*>((const char*)Bh_lds + byte);
                bl[fc] = *reinterpret_cast<const bf16x8*>((const char*)Bl_lds + byte);
            }
#pragma unroll
            for (int fr = 0; fr < 4; ++fr)
#pragma unroll
                for (int fc = 0; fc < 4; ++fc) {
                    acc[fr][fc] = __builtin_amdgcn_mfma_f32_16x16x32_bf16(ah[fr], bh[fc], acc[fr][fc], 0, 0, 0);
                    acc[fr][fc] = __builtin_amdgcn_mfma_f32_16x16x32_bf16(al[fr], bh[fc], acc[fr][fc], 0, 0, 0);
                    acc[fr][fc] = __builtin_amdgcn_mfma_f32_16x16x32_bf16(ah[fr], bl[fc], acc[fr][fc], 0, 0, 0);
                }
        }
    }
#pragma unroll
    for (int fc = 0; fc < 4; ++fc) {
        const int col = w * 64 + fc * 16 + (lane & 15);
        const float bv = bias[col];
#pragma unroll
        for (int fr = 0; fr < 4; ++fr)
#pragma unroll
            for (int ri = 0; ri < 4; ++ri) {
                const int gr = m0 + fr * 16 + (lane >> 4) * 4 + ri;
                const int orow = (gr & 7) * NTOT + (gr >> 3);
                C[(size_t)orow * 256 + col] = acc[fr][fc][ri] + bv;
            }
    }
}

// ---------------------------------------------------------------------------
// Generic query-side bf16x3 MFMA GEMM, M multiple of 64, K=256.
// B = pre-swizzled cat buffer rows (base row must be multiple of 8).
// MODE 0: single C (256 cols), row remap (r%rmod)*rmul + r/rmod, bias0.
// MODE 1: split outputs — cols 0-255 -> C0 (ld 256, bias0),
//         cols 256-383 -> C1 (ld 128, bias1); identity rows. N=384, grid.y=2.
// ---------------------------------------------------------------------------
template<int MODE>
__global__ __launch_bounds__(256, 2) void gemm_q_mfma(
    const float* __restrict__ A,
    const unsigned short* __restrict__ Bth, const unsigned short* __restrict__ Btl,
    const float* __restrict__ bias0, const float* __restrict__ bias1,
    float* __restrict__ C0, float* __restrict__ C1,
    const int N, const int rmod, const int rmul)
{
    __shared__ unsigned short Ah_lds[64 * 64];
    __shared__ unsigned short Al_lds[64 * 64];
    __shared__ unsigned short Bh_lds[256 * 64];
    __shared__ unsigned short Bl_lds[256 * 64];

    const int tid  = threadIdx.x;
    const int lane = tid & 63;
    const int w    = tid >> 6;
    const int m0   = blockIdx.x * 64;
    const int n0   = blockIdx.y * 256;
    const int ac   = min(256, N - n0);          // active cols this tile
    const bool active = (w * 64) < ac;
    const int cpw  = ac >> 4;                   // B chunks per wave
    const int rpp  = ac >> 3;                   // row-chunks per plane

    f32x4 acc[4][4];
#pragma unroll
    for (int i = 0; i < 4; ++i)
#pragma unroll
        for (int j = 0; j < 4; ++j) acc[i][j] = (f32x4){0.f, 0.f, 0.f, 0.f};

    for (int kc = 0; kc < 256; kc += 64) {
        __syncthreads();
#pragma unroll
        for (int u = 0; u < 4; ++u) {
            const int idx = tid + u * 256;
            const int row = idx >> 4;
            const int c4  = (idx & 15) * 4;
            const float4 av = *reinterpret_cast<const float4*>(
                &A[(size_t)(m0 + row) * 256 + kc + c4]);
            float r0, r1, r2, r3;
            const unsigned e0 = bf_hi(av.x, &r0);
            const unsigned e1 = bf_hi(av.y, &r1);
            const unsigned e2 = bf_hi(av.z, &r2);
            const unsigned e3 = bf_hi(av.w, &r3);
            uint2 hp, lp;
            hp.x = e0 | (e1 << 16);
            hp.y = e2 | (e3 << 16);
            lp.x = (unsigned)bf_rn(r0) | ((unsigned)bf_rn(r1) << 16);
            lp.y = (unsigned)bf_rn(r2) | ((unsigned)bf_rn(r3) << 16);
            const unsigned byte = (unsigned)(row * 128 + c4 * 2) ^ ((unsigned)(row & 7) << 4);
            *reinterpret_cast<uint2*>((char*)Ah_lds + byte) = hp;
            *reinterpret_cast<uint2*>((char*)Al_lds + byte) = lp;
        }
        {
            const int r8 = lane >> 3, sl = lane & 7;
            for (int i = 0; i < cpw; ++i) {
                const int chunk = w * cpw + i;
                const int plane = chunk >= rpp;
                const int crow  = (plane ? chunk - rpp : chunk) * 8;     // local row
                const unsigned short* gb = plane ? Btl : Bth;
                const size_t gbyte = (size_t)(n0 + crow + r8) * 512 + (size_t)kc * 2 + (size_t)sl * 16;
                unsigned short* lbase = (plane ? Bl_lds : Bh_lds) + crow * 64;
                __builtin_amdgcn_global_load_lds(
                    (const __attribute__((address_space(1))) void*)((const char*)gb + gbyte),
                    (__attribute__((address_space(3))) void*)lbase,
                    16, 0, 0);
            }
        }
        __syncthreads();
        if (active) {
#pragma unroll
            for (int kk = 0; kk < 2; ++kk) {
                bf16x8 ah[4], al[4], bh[4], bl[4];
                const int slot = kk * 4 + (lane >> 4);
#pragma unroll
                for (int fr = 0; fr < 4; ++fr) {
                    const int row = fr * 16 + (lane & 15);
                    const unsigned byte = (unsigned)(row * 128) + ((unsigned)(slot ^ (row & 7)) << 4);
                    ah[fr] = *reinterpret_cast<const bf16x8*>((const char*)Ah_lds + byte);
                    al[fr] = *reinterpret_cast<const bf16x8*>((const char*)Al_lds + byte);
                }
#pragma unroll
                for (int fc = 0; fc < 4; ++fc) {
                    const int n = w * 64 + fc * 16 + (lane & 15);
                    const unsigned byte = (unsigned)(n * 128) + ((unsigned)(slot ^ (n & 7)) << 4);
                    bh[fc] = *reinterpret_cast<const bf16x8*>((const char*)Bh_lds + byte);
                    bl[fc] = *reinterpret_cast<const bf16x8*>((const char*)Bl_lds + byte);
                }
#pragma unroll
                for (int fr = 0; fr < 4; ++fr)
#pragma unroll
                    for (int fc = 0; fc < 4; ++fc) {
                        acc[fr][fc] = __builtin_amdgcn_mfma_f32_16x16x32_bf16(ah[fr], bh[fc], acc[fr][fc], 0, 0, 0);
                        acc[fr][fc] = __builtin_amdgcn_mfma_f32_16x16x32_bf16(al[fr], bh[fc], acc[fr][fc], 0, 0, 0);
                        acc[fr][fc] = __builtin_amdgcn_mfma_f32_16x16x32_bf16(ah[fr], bl[fc], acc[fr][fc], 0, 0, 0);
                    }
            }
        }
    }
    if (!active) return;
#pragma unroll
    for (int fc = 0; fc < 4; ++fc) {
        const int colg = n0 + w * 64 + fc * 16 + (lane & 15);
#pragma unroll
        for (int fr = 0; fr < 4; ++fr)
#pragma unroll
            for (int ri = 0; ri < 4; ++ri) {
                const int gr = m0 + fr * 16 + (lane >> 4) * 4 + ri;
                const float v = acc[fr][fc][ri];
                if (MODE == 0) {
                    const int orow = (gr % rmod) * rmul + gr / rmod;
                    C0[(size_t)orow * 256 + colg] = v + bias0[colg];
                } else {
                    if (colg < 256) C0[(size_t)gr * 256 + colg] = v + bias0[colg];
                    else            C1[(size_t)gr * 128 + colg - 256] = v + bias1[colg - 256];
                }
            }
    }
}

// ---------------------------------------------------------------------------
// Sampling (unchanged): one wave per (b, q, h).
// ---------------------------------------------------------------------------
__global__ __launch_bounds__(256) void msda_sample(
    const float* __restrict__ vproj, const float* __restrict__ off_raw,
    const float* __restrict__ attn_raw, const float* __restrict__ refp,
    float* __restrict__ tmp)
{
    const int lane = threadIdx.x & 63;
    const int widx = blockIdx.x * 4 + (threadIdx.x >> 6);
    const int h  = widx & 7;
    const int bq = widx >> 3;
    const int b  = bq / QQ;
    const int qi = bq - b * QQ;
    const int row_q = qi * BBATCH + b;

    const int s0 = lane & 15;
    const int l0 = s0 >> 2;
    float a = attn_raw[row_q * 128 + h * 16 + s0];
    float m = a;
#pragma unroll
    for (int msk = 8; msk >= 1; msk >>= 1) m = fmaxf(m, __shfl_xor(m, msk));
    const float e = __expf(a - m);
    float ssum = e;
#pragma unroll
    for (int msk = 8; msk >= 1; msk >>= 1) ssum += __shfl_xor(ssum, msk);
    const float wv = e / ssum;

    const float offx = off_raw[row_q * 256 + (h * 16 + s0) * 2 + 0];
    const float offy = off_raw[row_q * 256 + (h * 16 + s0) * 2 + 1];
    const float rx = refp[row_q * 2 + 0];
    const float ry = refp[row_q * 2 + 1];
    const float Wf = (float)(128 >> l0);
    float lx = rx + offx / (Wf + 1e-6f);
    float ly = ry + offy / (Wf + 1e-6f);
    lx = fminf(fmaxf(lx, 0.f), 1.f);
    ly = fminf(fmaxf(ly, 0.f), 1.f);
    const float xv = lx * Wf - 0.5f;
    const float yv = ly * Wf - 0.5f;

    const int c = lane & 31;
    const int sbase = (lane >> 5) * 8;
    const float* __restrict__ vb = vproj + (size_t)b * NTOT * 256 + h * 32 + c;

    float acc = 0.f;
#pragma unroll
    for (int i = 0; i < 8; ++i) {
        const int s = sbase + i;
        const float xs = __shfl(xv, s);
        const float ys = __shfl(yv, s);
        const float ws = __shfl(wv, s);
        const int l = s >> 2;
        const int Wl = 128 >> l;
        const int start = (65536 - (65536 >> (2 * l))) / 3;
        const float x0f = floorf(xs), y0f = floorf(ys);
        const float fx = xs - x0f, fy = ys - y0f;
        const int x0 = (int)x0f, y0 = (int)y0f;
        const int x1 = x0 + 1,   y1 = y0 + 1;
        const float vx0 = (x0 >= 0 && x0 < Wl) ? 1.f : 0.f;
        const float vx1 = (x1 >= 0 && x1 < Wl) ? 1.f : 0.f;
        const float vy0 = (y0 >= 0 && y0 < Wl) ? 1.f : 0.f;
        const float vy1 = (y1 >= 0 && y1 < Wl) ? 1.f : 0.f;
        const int xc0 = min(max(x0, 0), Wl - 1);
        const int xc1 = min(max(x1, 0), Wl - 1);
        const int yc0 = min(max(y0, 0), Wl - 1);
        const int yc1 = min(max(y1, 0), Wl - 1);
        const float* base = vb + (size_t)start * 256;
        const float v00 = base[(size_t)(yc0 * Wl + xc0) * 256];
        const float v10 = base[(size_t)(yc0 * Wl + xc1) * 256];
        const float v01 = base[(size_t)(yc1 * Wl + xc0) * 256];
        const float v11 = base[(size_t)(yc1 * Wl + xc1) * 256];
        const float w00 = (1.f - fx) * (1.f - fy) * vx0 * vy0;
        const float w10 = fx * (1.f - fy) * vx1 * vy0;
        const float w01 = (1.f - fx) * fy * vx0 * vy1;
        const float w11 = fx * fy * vx1 * vy1;
        acc += ws * (w00 * v00 + w10 * v10 + w01 * v01 + w11 * v11);
    }
    acc += __shfl_xor(acc, 32);
    if (lane < 32) tmp[(size_t)bq * 256 + h * 32 + c] = acc;
}

// ---------------------------------------------------------------------------
extern "C" void kernel_launch(void* const* d_in, const int* in_sizes, int n_in,
                              void* d_out, int out_size, void* d_ws, size_t ws_size,
                              hipStream_t stream) {
    (void)in_sizes; (void)n_in; (void)out_size; (void)ws_size;

    const float* query  = (const float*)d_in[0];
    const float* refp   = (const float*)d_in[1];
    const float* value  = (const float*)d_in[2];
    const float* W_v    = (const float*)d_in[5];
    const float* b_v    = (const float*)d_in[6];
    const float* W_off  = (const float*)d_in[7];
    const float* b_off  = (const float*)d_in[8];
    const float* W_attn = (const float*)d_in[9];
    const float* b_attn = (const float*)d_in[10];
    const float* W_out  = (const float*)d_in[11];
    const float* b_out  = (const float*)d_in[12];
    float* out = (float*)d_out;

    // workspace (floats): vproj 44,564,480 | off 2,048,000 | attn 1,024,000 |
    // tmp 2,048,000 | Wcat hi/lo 163,840 ush each (0.66 MB) -> ~199.4 MB.
    // Value-GEMM Bt hi/lo (128 KB each) borrow tmp's head: read only by the
    // value GEMM, fully overwritten later by the sampler.
    float* vproj    = (float*)d_ws;
    float* off_raw  = vproj + (size_t)44564480;
    float* attn_raw = off_raw + 2048000;
    float* tmp      = attn_raw + 1024000;
    unsigned short* Bt_h   = (unsigned short*)tmp;
    unsigned short* Bt_l   = Bt_h + 65536;
    unsigned short* Wcat_h = (unsigned short*)(tmp + 2048000);
    unsigned short* Wcat_l = Wcat_h + 640 * 256;

    const dim3 blk(256);
    // weight conversions
    conv_wv<<<dim3(32), blk, 0, stream>>>(W_v, Bt_h, Bt_l);
    conv_wcat<<<dim3(80), blk, 0, stream>>>(W_off, W_attn, W_out, Wcat_h, Wcat_l);
    // value projection: (174080 x 256) @ (256 x 256)
    gemm_value_mfma<<<dim3(2720), blk, 0, stream>>>(value, Bt_h, Bt_l, b_v, vproj);
    // fused offsets+attn: (8000 x 256) @ (256 x 384), identity rows
    gemm_q_mfma<1><<<dim3(125, 2), blk, 0, stream>>>(
        query, Wcat_h, Wcat_l, b_off, b_attn, off_raw, attn_raw, 384, 0, 0);
    // sampling: 64000 waves
    msda_sample<<<dim3(16000), blk, 0, stream>>>(vproj, off_raw, attn_raw, refp, tmp);
    // output projection: (8000 x 256) @ (256 x 256), rows b*1000+q -> q*8+b
    gemm_q_mfma<0><<<dim3(125, 1), blk, 0, stream>>>(
        tmp, Wcat_h + 384 * 256, Wcat_l + 384 * 256, b_out, nullptr,
        out, nullptr, 256, 1000, 8);
}

// Round 11
// 424.595 us; speedup vs baseline: 1.3945x; 1.0202x over previous
//
#include <hip/hip_runtime.h>
#include <math.h>

#define QQ     1000
#define BBATCH 8
#define NTOT   21760

typedef __bf16 bf16x8 __attribute__((ext_vector_type(8)));
typedef float  f32x4  __attribute__((ext_vector_type(4)));

// fp32 -> bf16 (RNE) hi part, remainder out
__device__ __forceinline__ unsigned short bf_hi(float f, float* rem) {
    unsigned u = __builtin_bit_cast(unsigned, f);
    unsigned r = (u + 0x7FFFu + ((u >> 16) & 1u)) >> 16;
    float hf = __builtin_bit_cast(float, r << 16);
    *rem = f - hf;
    return (unsigned short)r;
}
__device__ __forceinline__ unsigned short bf_rn(float f) {
    unsigned u = __builtin_bit_cast(unsigned, f);
    return (unsigned short)((u + 0x7FFFu + ((u >> 16) & 1u)) >> 16);
}

// ---------------------------------------------------------------------------
// Pre-pass A: W_v (256k x 256n fp32) -> Bt_hi/Bt_lo bf16, layout [n][k],
// XOR-swizzled per 64-k chunk: 16B slot s stored at s^(n&7).
// ---------------------------------------------------------------------------
__global__ __launch_bounds__(256) void conv_wv(
    const float* __restrict__ Wv,
    unsigned short* __restrict__ Bh, unsigned short* __restrict__ Bl)
{
    const int tid = threadIdx.x;
    const int n   = blockIdx.x * 8 + (tid >> 5);
    const int oct = tid & 31;
    const int k0  = oct * 8;
    float r0, r1, r2, r3, r4, r5, r6, r7;
    const unsigned h0 = bf_hi(Wv[(k0+0)*256 + n], &r0);
    const unsigned h1 = bf_hi(Wv[(k0+1)*256 + n], &r1);
    const unsigned h2 = bf_hi(Wv[(k0+2)*256 + n], &r2);
    const unsigned h3 = bf_hi(Wv[(k0+3)*256 + n], &r3);
    const unsigned h4 = bf_hi(Wv[(k0+4)*256 + n], &r4);
    const unsigned h5 = bf_hi(Wv[(k0+5)*256 + n], &r5);
    const unsigned h6 = bf_hi(Wv[(k0+6)*256 + n], &r6);
    const unsigned h7 = bf_hi(Wv[(k0+7)*256 + n], &r7);
    uint4 hv, lv;
    hv.x = h0 | (h1 << 16); hv.y = h2 | (h3 << 16);
    hv.z = h4 | (h5 << 16); hv.w = h6 | (h7 << 16);
    lv.x = (unsigned)bf_rn(r0) | ((unsigned)bf_rn(r1) << 16);
    lv.y = (unsigned)bf_rn(r2) | ((unsigned)bf_rn(r3) << 16);
    lv.z = (unsigned)bf_rn(r4) | ((unsigned)bf_rn(r5) << 16);
    lv.w = (unsigned)bf_rn(r6) | ((unsigned)bf_rn(r7) << 16);
    const int c  = oct >> 3;
    const int sp = (oct & 7) ^ (n & 7);
    const size_t byte = (size_t)n * 512 + (size_t)c * 128 + (size_t)sp * 16;
    *reinterpret_cast<uint4*>((char*)Bh + byte) = hv;
    *reinterpret_cast<uint4*>((char*)Bl + byte) = lv;
}

// ---------------------------------------------------------------------------
// Pre-pass B: [W_off(256n) | W_attn(128n) | W_out(256n)] -> 640-row cat buffer,
// same transposed/swizzled hi-lo layout. Grid 80 x 256.
// ---------------------------------------------------------------------------
__global__ __launch_bounds__(256) void conv_wcat(
    const float* __restrict__ W_off, const float* __restrict__ W_attn,
    const float* __restrict__ W_out,
    unsigned short* __restrict__ Bh, unsigned short* __restrict__ Bl)
{
    const int tid = threadIdx.x;
    const int n   = blockIdx.x * 8 + (tid >> 5);
    const int oct = tid & 31;
    const int k0  = oct * 8;
    const float* src; int col, ld;
    if (n < 256)      { src = W_off;  col = n;       ld = 256; }
    else if (n < 384) { src = W_attn; col = n - 256; ld = 128; }
    else              { src = W_out;  col = n - 384; ld = 256; }
    unsigned hw[8], lw[8];
#pragma unroll
    for (int j = 0; j < 8; ++j) {
        float r;
        hw[j] = bf_hi(src[(size_t)(k0 + j) * ld + col], &r);
        lw[j] = bf_rn(r);
    }
    uint4 hv, lv;
    hv.x = hw[0] | (hw[1] << 16); hv.y = hw[2] | (hw[3] << 16);
    hv.z = hw[4] | (hw[5] << 16); hv.w = hw[6] | (hw[7] << 16);
    lv.x = lw[0] | (lw[1] << 16); lv.y = lw[2] | (lw[3] << 16);
    lv.z = lw[4] | (lw[5] << 16); lv.w = lw[6] | (lw[7] << 16);
    const int c  = oct >> 3;
    const int sp = (oct & 7) ^ (n & 7);
    const size_t byte = (size_t)n * 512 + (size_t)c * 128 + (size_t)sp * 16;
    *reinterpret_cast<uint4*>((char*)Bh + byte) = hv;
    *reinterpret_cast<uint4*>((char*)Bl + byte) = lv;
}

// ---------------------------------------------------------------------------
// Value projection via bf16x3 MFMA. Round-10: BN 256->128 (grid.y=2), LDS
// 80->48 KB -> 3 blocks/CU (was 2). A read twice but L3-resident (round-9
// FETCH 91MB < 178MB A). Each wave: 64 rows x 32 cols, acc[4][2].
// ---------------------------------------------------------------------------
__global__ __launch_bounds__(256, 3) void gemm_value_mfma(
    const float* __restrict__ A,
    const unsigned short* __restrict__ Bth, const unsigned short* __restrict__ Btl,
    const float* __restrict__ bias, float* __restrict__ C)
{
    __shared__ unsigned short Ah_lds[64 * 64];     // 8 KB
    __shared__ unsigned short Al_lds[64 * 64];     // 8 KB
    __shared__ unsigned short Bh_lds[128 * 64];    // 16 KB
    __shared__ unsigned short Bl_lds[128 * 64];    // 16 KB

    const int tid  = threadIdx.x;
    const int lane = tid & 63;
    const int w    = tid >> 6;
    const int m0   = blockIdx.x * 64;
    const int n0   = blockIdx.y * 128;

    f32x4 acc[4][2];
#pragma unroll
    for (int i = 0; i < 4; ++i)
#pragma unroll
        for (int j = 0; j < 2; ++j) acc[i][j] = (f32x4){0.f, 0.f, 0.f, 0.f};

    for (int kc = 0; kc < 256; kc += 64) {
        __syncthreads();
        // --- A stage: fp32 load -> split bf16 -> swizzled ds_write ---
#pragma unroll
        for (int u = 0; u < 4; ++u) {
            const int idx = tid + u * 256;
            const int row = idx >> 4;
            const int c4  = (idx & 15) * 4;
            const float4 av = *reinterpret_cast<const float4*>(
                &A[(size_t)(m0 + row) * 256 + kc + c4]);
            float r0, r1, r2, r3;
            const unsigned e0 = bf_hi(av.x, &r0);
            const unsigned e1 = bf_hi(av.y, &r1);
            const unsigned e2 = bf_hi(av.z, &r2);
            const unsigned e3 = bf_hi(av.w, &r3);
            uint2 hp, lp;
            hp.x = e0 | (e1 << 16);
            hp.y = e2 | (e3 << 16);
            lp.x = (unsigned)bf_rn(r0) | ((unsigned)bf_rn(r1) << 16);
            lp.y = (unsigned)bf_rn(r2) | ((unsigned)bf_rn(r3) << 16);
            const unsigned byte = (unsigned)(row * 128 + c4 * 2) ^ ((unsigned)(row & 7) << 4);
            *reinterpret_cast<uint2*>((char*)Ah_lds + byte) = hp;
            *reinterpret_cast<uint2*>((char*)Al_lds + byte) = lp;
        }
        // --- B stage: 32 chunks (16 hi + 16 lo rows-of-8), 8 per wave ---
        {
            const int r8 = lane >> 3, sl = lane & 7;
#pragma unroll
            for (int i = 0; i < 8; ++i) {
                const int chunk = w * 8 + i;        // 0..31
                const int plane = chunk >> 4;
                const int crow  = (chunk & 15) * 8; // local row 0..120
                const unsigned short* gb = plane ? Btl : Bth;
                const size_t gbyte = (size_t)(n0 + crow + r8) * 512 + (size_t)kc * 2 + (size_t)sl * 16;
                unsigned short* lbase = (plane ? Bl_lds : Bh_lds) + crow * 64;
                __builtin_amdgcn_global_load_lds(
                    (const __attribute__((address_space(1))) void*)((const char*)gb + gbyte),
                    (__attribute__((address_space(3))) void*)lbase,
                    16, 0, 0);
            }
        }
        __syncthreads();
        // --- compute: 2 k-chunks x (4 row x 2 col) frags x 3 passes ---
#pragma unroll
        for (int kk = 0; kk < 2; ++kk) {
            bf16x8 ah[4], al[4], bh[2], bl[2];
            const int slot = kk * 4 + (lane >> 4);
#pragma unroll
            for (int fr = 0; fr < 4; ++fr) {
                const int row = fr * 16 + (lane & 15);
                const unsigned byte = (unsigned)(row * 128) + ((unsigned)(slot ^ (row & 7)) << 4);
                ah[fr] = *reinterpret_cast<const bf16x8*>((const char*)Ah_lds + byte);
                al[fr] = *reinterpret_cast<const bf16x8*>((const char*)Al_lds + byte);
            }
#pragma unroll
            for (int fc = 0; fc < 2; ++fc) {
                const int n = w * 32 + fc * 16 + (lane & 15);   // local col 0..127
                const unsigned byte = (unsigned)(n * 128) + ((unsigned)(slot ^ (n & 7)) << 4);
                bh[fc] = *reinterpret_cast<const bf16x8*>((const char*)Bh_lds + byte);
                bl[fc] = *reinterpret_cast<const bf16x8*>((const char*)Bl_lds + byte);
            }
#pragma unroll
            for (int fr = 0; fr < 4; ++fr)
#pragma unroll
                for (int fc = 0; fc < 2; ++fc) {
                    acc[fr][fc] = __builtin_amdgcn_mfma_f32_16x16x32_bf16(ah[fr], bh[fc], acc[fr][fc], 0, 0, 0);
                    acc[fr][fc] = __builtin_amdgcn_mfma_f32_16x16x32_bf16(al[fr], bh[fc], acc[fr][fc], 0, 0, 0);
                    acc[fr][fc] = __builtin_amdgcn_mfma_f32_16x16x32_bf16(ah[fr], bl[fc], acc[fr][fc], 0, 0, 0);
                }
        }
    }
    // epilogue: bias + permuted-row scalar stores
#pragma unroll
    for (int fc = 0; fc < 2; ++fc) {
        const int col = n0 + w * 32 + fc * 16 + (lane & 15);
        const float bv = bias[col];
#pragma unroll
        for (int fr = 0; fr < 4; ++fr)
#pragma unroll
            for (int ri = 0; ri < 4; ++ri) {
                const int gr = m0 + fr * 16 + (lane >> 4) * 4 + ri;   // r = n*8+b
                const int orow = (gr & 7) * NTOT + (gr >> 3);         // b*21760+n
                C[(size_t)orow * 256 + col] = acc[fr][fc][ri] + bv;
            }
    }
}

// ---------------------------------------------------------------------------
// Generic query-side bf16x3 MFMA GEMM (unchanged from round 9; verified).
// ---------------------------------------------------------------------------
template<int MODE>
__global__ __launch_bounds__(256, 2) void gemm_q_mfma(
    const float* __restrict__ A,
    const unsigned short* __restrict__ Bth, const unsigned short* __restrict__ Btl,
    const float* __restrict__ bias0, const float* __restrict__ bias1,
    float* __restrict__ C0, float* __restrict__ C1,
    const int N, const int rmod, const int rmul)
{
    __shared__ unsigned short Ah_lds[64 * 64];
    __shared__ unsigned short Al_lds[64 * 64];
    __shared__ unsigned short Bh_lds[256 * 64];
    __shared__ unsigned short Bl_lds[256 * 64];

    const int tid  = threadIdx.x;
    const int lane = tid & 63;
    const int w    = tid >> 6;
    const int m0   = blockIdx.x * 64;
    const int n0   = blockIdx.y * 256;
    const int ac   = min(256, N - n0);
    const bool active = (w * 64) < ac;
    const int cpw  = ac >> 4;
    const int rpp  = ac >> 3;

    f32x4 acc[4][4];
#pragma unroll
    for (int i = 0; i < 4; ++i)
#pragma unroll
        for (int j = 0; j < 4; ++j) acc[i][j] = (f32x4){0.f, 0.f, 0.f, 0.f};

    for (int kc = 0; kc < 256; kc += 64) {
        __syncthreads();
#pragma unroll
        for (int u = 0; u < 4; ++u) {
            const int idx = tid + u * 256;
            const int row = idx >> 4;
            const int c4  = (idx & 15) * 4;
            const float4 av = *reinterpret_cast<const float4*>(
                &A[(size_t)(m0 + row) * 256 + kc + c4]);
            float r0, r1, r2, r3;
            const unsigned e0 = bf_hi(av.x, &r0);
            const unsigned e1 = bf_hi(av.y, &r1);
            const unsigned e2 = bf_hi(av.z, &r2);
            const unsigned e3 = bf_hi(av.w, &r3);
            uint2 hp, lp;
            hp.x = e0 | (e1 << 16);
            hp.y = e2 | (e3 << 16);
            lp.x = (unsigned)bf_rn(r0) | ((unsigned)bf_rn(r1) << 16);
            lp.y = (unsigned)bf_rn(r2) | ((unsigned)bf_rn(r3) << 16);
            const unsigned byte = (unsigned)(row * 128 + c4 * 2) ^ ((unsigned)(row & 7) << 4);
            *reinterpret_cast<uint2*>((char*)Ah_lds + byte) = hp;
            *reinterpret_cast<uint2*>((char*)Al_lds + byte) = lp;
        }
        {
            const int r8 = lane >> 3, sl = lane & 7;
            for (int i = 0; i < cpw; ++i) {
                const int chunk = w * cpw + i;
                const int plane = chunk >= rpp;
                const int crow  = (plane ? chunk - rpp : chunk) * 8;
                const unsigned short* gb = plane ? Btl : Bth;
                const size_t gbyte = (size_t)(n0 + crow + r8) * 512 + (size_t)kc * 2 + (size_t)sl * 16;
                unsigned short* lbase = (plane ? Bl_lds : Bh_lds) + crow * 64;
                __builtin_amdgcn_global_load_lds(
                    (const __attribute__((address_space(1))) void*)((const char*)gb + gbyte),
                    (__attribute__((address_space(3))) void*)lbase,
                    16, 0, 0);
            }
        }
        __syncthreads();
        if (active) {
#pragma unroll
            for (int kk = 0; kk < 2; ++kk) {
                bf16x8 ah[4], al[4], bh[4], bl[4];
                const int slot = kk * 4 + (lane >> 4);
#pragma unroll
                for (int fr = 0; fr < 4; ++fr) {
                    const int row = fr * 16 + (lane & 15);
                    const unsigned byte = (unsigned)(row * 128) + ((unsigned)(slot ^ (row & 7)) << 4);
                    ah[fr] = *reinterpret_cast<const bf16x8*>((const char*)Ah_lds + byte);
                    al[fr] = *reinterpret_cast<const bf16x8*>((const char*)Al_lds + byte);
                }
#pragma unroll
                for (int fc = 0; fc < 4; ++fc) {
                    const int n = w * 64 + fc * 16 + (lane & 15);
                    const unsigned byte = (unsigned)(n * 128) + ((unsigned)(slot ^ (n & 7)) << 4);
                    bh[fc] = *reinterpret_cast<const bf16x8*>((const char*)Bh_lds + byte);
                    bl[fc] = *reinterpret_cast<const bf16x8*>((const char*)Bl_lds + byte);
                }
#pragma unroll
                for (int fr = 0; fr < 4; ++fr)
#pragma unroll
                    for (int fc = 0; fc < 4; ++fc) {
                        acc[fr][fc] = __builtin_amdgcn_mfma_f32_16x16x32_bf16(ah[fr], bh[fc], acc[fr][fc], 0, 0, 0);
                        acc[fr][fc] = __builtin_amdgcn_mfma_f32_16x16x32_bf16(al[fr], bh[fc], acc[fr][fc], 0, 0, 0);
                        acc[fr][fc] = __builtin_amdgcn_mfma_f32_16x16x32_bf16(ah[fr], bl[fc], acc[fr][fc], 0, 0, 0);
                    }
            }
        }
    }
    if (!active) return;
#pragma unroll
    for (int fc = 0; fc < 4; ++fc) {
        const int colg = n0 + w * 64 + fc * 16 + (lane & 15);
#pragma unroll
        for (int fr = 0; fr < 4; ++fr)
#pragma unroll
            for (int ri = 0; ri < 4; ++ri) {
                const int gr = m0 + fr * 16 + (lane >> 4) * 4 + ri;
                const float v = acc[fr][fc][ri];
                if (MODE == 0) {
                    const int orow = (gr % rmod) * rmul + gr / rmod;
                    C0[(size_t)orow * 256 + colg] = v + bias0[colg];
                } else {
                    if (colg < 256) C0[(size_t)gr * 256 + colg] = v + bias0[colg];
                    else            C1[(size_t)gr * 128 + colg - 256] = v + bias1[colg - 256];
                }
            }
    }
}

// ---------------------------------------------------------------------------
// Sampling v2: one wave per (b, q, h). Gather restructured: lane =
// (sample-parity)*32 + corner*8 + c4 -> one dwordx4 per lane fetches
// 2 samples x 4 corners x 128 B per wave-iteration (8 iters for 16 samples).
// 4x fewer VMEM instructions vs v1 (same bytes). Per-corner partials reduce
// once at the end via xor 8/16/32 on float4.
// ---------------------------------------------------------------------------
__global__ __launch_bounds__(256) void msda_sample(
    const float* __restrict__ vproj, const float* __restrict__ off_raw,
    const float* __restrict__ attn_raw, const float* __restrict__ refp,
    float* __restrict__ tmp)
{
    const int lane = threadIdx.x & 63;
    const int widx = blockIdx.x * 4 + (threadIdx.x >> 6);
    const int h  = widx & 7;
    const int bq = widx >> 3;                 // b*QQ + qi
    const int b  = bq / QQ;
    const int qi = bq - b * QQ;
    const int row_q = qi * BBATCH + b;

    // --- per-sample metadata (sample s0 = lane & 15, replicated x4) ---
    const int s0 = lane & 15;
    const int l0 = s0 >> 2;
    float a = attn_raw[row_q * 128 + h * 16 + s0];
    float m = a;
#pragma unroll
    for (int msk = 8; msk >= 1; msk >>= 1) m = fmaxf(m, __shfl_xor(m, msk));
    const float e = __expf(a - m);
    float ssum = e;
#pragma unroll
    for (int msk = 8; msk >= 1; msk >>= 1) ssum += __shfl_xor(ssum, msk);
    const float wv = e / ssum;

    const float offx = off_raw[row_q * 256 + (h * 16 + s0) * 2 + 0];
    const float offy = off_raw[row_q * 256 + (h * 16 + s0) * 2 + 1];
    const float rx = refp[row_q * 2 + 0];
    const float ry = refp[row_q * 2 + 1];
    const float Wf = (float)(128 >> l0);      // H == W at every level
    float lx = rx + offx / (Wf + 1e-6f);
    float ly = ry + offy / (Wf + 1e-6f);
    lx = fminf(fmaxf(lx, 0.f), 1.f);
    ly = fminf(fmaxf(ly, 0.f), 1.f);
    const float xv = lx * Wf - 0.5f;          // grid_sample align_corners=False
    const float yv = ly * Wf - 0.5f;

    // --- gather: lane = half*32 + corner*8 + c4 ---
    const int half   = lane >> 5;
    const int corner = (lane >> 3) & 3;
    const int c4     = lane & 7;
    const int dx = corner & 1, dy = corner >> 1;
    const float* __restrict__ vb = vproj + (size_t)b * NTOT * 256 + h * 32 + c4 * 4;

    f32x4 pacc = (f32x4){0.f, 0.f, 0.f, 0.f};
#pragma unroll
    for (int i = 0; i < 8; ++i) {
        const int s = i * 2 + half;           // half 0: even samples, half 1: odd
        const float xs = __shfl(xv, s);
        const float ys = __shfl(yv, s);
        const float ws = __shfl(wv, s);
        const int l = s >> 2;
        const int Wl = 128 >> l;
        const int start = (65536 - (65536 >> (2 * l))) / 3;
        const float x0f = floorf(xs), y0f = floorf(ys);
        const float fx = xs - x0f, fy = ys - y0f;
        const int xi = (int)x0f + dx;
        const int yi = (int)y0f + dy;
        const bool ok = (xi >= 0) && (xi < Wl) && (yi >= 0) && (yi < Wl);
        const int xc = min(max(xi, 0), Wl - 1);
        const int yc = min(max(yi, 0), Wl - 1);
        const float wc = (dx ? fx : 1.f - fx) * (dy ? fy : 1.f - fy) * (ok ? ws : 0.f);
        const float4 v4 = *reinterpret_cast<const float4*>(
            vb + (size_t)(start + yc * Wl + xc) * 256);
        pacc[0] += wc * v4.x;
        pacc[1] += wc * v4.y;
        pacc[2] += wc * v4.z;
        pacc[3] += wc * v4.w;
    }
    // reduce corners (xor 8, 16) then halves (xor 32)
#pragma unroll
    for (int msk = 8; msk <= 32; msk <<= 1) {
        pacc[0] += __shfl_xor(pacc[0], msk);
        pacc[1] += __shfl_xor(pacc[1], msk);
        pacc[2] += __shfl_xor(pacc[2], msk);
        pacc[3] += __shfl_xor(pacc[3], msk);
    }
    if (lane < 8) {
        float4 o; o.x = pacc[0]; o.y = pacc[1]; o.z = pacc[2]; o.w = pacc[3];
        *reinterpret_cast<float4*>(&tmp[(size_t)bq * 256 + h * 32 + lane * 4]) = o;
    }
}

// ---------------------------------------------------------------------------
extern "C" void kernel_launch(void* const* d_in, const int* in_sizes, int n_in,
                              void* d_out, int out_size, void* d_ws, size_t ws_size,
                              hipStream_t stream) {
    (void)in_sizes; (void)n_in; (void)out_size; (void)ws_size;

    const float* query  = (const float*)d_in[0];
    const float* refp   = (const float*)d_in[1];
    const float* value  = (const float*)d_in[2];
    const float* W_v    = (const float*)d_in[5];
    const float* b_v    = (const float*)d_in[6];
    const float* W_off  = (const float*)d_in[7];
    const float* b_off  = (const float*)d_in[8];
    const float* W_attn = (const float*)d_in[9];
    const float* b_attn = (const float*)d_in[10];
    const float* W_out  = (const float*)d_in[11];
    const float* b_out  = (const float*)d_in[12];
    float* out = (float*)d_out;

    // workspace (floats): vproj 44,564,480 | off 2,048,000 | attn 1,024,000 |
    // tmp 2,048,000 | Wcat hi/lo. Bt hi/lo borrow tmp's head (dead before
    // the sampler overwrites tmp).
    float* vproj    = (float*)d_ws;
    float* off_raw  = vproj + (size_t)44564480;
    float* attn_raw = off_raw + 2048000;
    float* tmp      = attn_raw + 1024000;
    unsigned short* Bt_h   = (unsigned short*)tmp;
    unsigned short* Bt_l   = Bt_h + 65536;
    unsigned short* Wcat_h = (unsigned short*)(tmp + 2048000);
    unsigned short* Wcat_l = Wcat_h + 640 * 256;

    const dim3 blk(256);
    // weight conversions
    conv_wv<<<dim3(32), blk, 0, stream>>>(W_v, Bt_h, Bt_l);
    conv_wcat<<<dim3(80), blk, 0, stream>>>(W_off, W_attn, W_out, Wcat_h, Wcat_l);
    // value projection: (174080 x 256) @ (256 x 256), BM=64 BN=128
    gemm_value_mfma<<<dim3(2720, 2), blk, 0, stream>>>(value, Bt_h, Bt_l, b_v, vproj);
    // fused offsets+attn: (8000 x 256) @ (256 x 384), identity rows
    gemm_q_mfma<1><<<dim3(125, 2), blk, 0, stream>>>(
        query, Wcat_h, Wcat_l, b_off, b_attn, off_raw, attn_raw, 384, 0, 0);
    // sampling: 64000 waves
    msda_sample<<<dim3(16000), blk, 0, stream>>>(vproj, off_raw, attn_raw, refp, tmp);
    // output projection: (8000 x 256) @ (256 x 256), rows b*1000+q -> q*8+b
    gemm_q_mfma<0><<<dim3(125, 1), blk, 0, stream>>>(
        tmp, Wcat_h + 384 * 256, Wcat_l + 384 * 256, b_out, nullptr,
        out, nullptr, 256, 1000, 8);
}